// Round 1
// baseline (194.660 us; speedup 1.0000x reference)
//
#include <hip/hip_runtime.h>
#include <stdint.h>

#define Bb 2
#define Nn 16384
#define Dd 128
#define Qq 4096
#define Ee 256
#define NSPLIT 8
#define NCHUNK 2048   // Nn / NSPLIT
#define KV 64
#define NITER 32      // NCHUNK / KV

typedef __bf16 bf16x8 __attribute__((ext_vector_type(8)));
typedef float floatx4 __attribute__((ext_vector_type(4)));

__device__ __forceinline__ unsigned f2bf1(float f) {
  unsigned u = __float_as_uint(f);
  u = u + 0x7FFFu + ((u >> 16) & 1u);   // RNE; inputs are finite
  return u >> 16;
}
__device__ __forceinline__ unsigned f2bf2(float lo, float hi) {
  return f2bf1(lo) | (f2bf1(hi) << 16);
}

// ---------------- K1: LayerNorm -> xn bf16 [B][N][D], one wave per row ----
__global__ __launch_bounds__(256) void k_ln(const float* __restrict__ x,
    const float* __restrict__ gamma, const float* __restrict__ beta,
    unsigned* __restrict__ xn) {
  int row = blockIdx.x * 4 + (threadIdx.x >> 6);
  int lane = threadIdx.x & 63;
  float2 v = ((const float2*)x)[(size_t)row * 64 + lane];
  float s = v.x + v.y, s2 = v.x * v.x + v.y * v.y;
#pragma unroll
  for (int off = 32; off; off >>= 1) {
    s += __shfl_xor(s, off);
    s2 += __shfl_xor(s2, off);
  }
  float mu = s * (1.0f / 128.0f);
  float var = s2 * (1.0f / 128.0f) - mu * mu;
  float rs = rsqrtf(var + 1e-5f);
  float2 g = ((const float2*)gamma)[lane];
  float2 bt = ((const float2*)beta)[lane];
  float y0 = (v.x - mu) * rs * g.x + bt.x;
  float y1 = (v.y - mu) * rs * g.y + bt.y;
  xn[(size_t)row * 64 + lane] = f2bf2(y0, y1);
}

// ---------------- K1b: cast queries (prescaled by SCALE*log2e) and W ------
__global__ __launch_bounds__(256) void k_cast(const float* __restrict__ queries,
    const float* __restrict__ W, unsigned short* __restrict__ qb,
    unsigned short* __restrict__ wb) {
  int i = blockIdx.x * 256 + threadIdx.x;
  const float QSC = 0.08838834764831845f * 1.4426950408889634f; // D^-0.5 * log2(e)
  if (i < Qq * Dd) {
    qb[i] = (unsigned short)f2bf1(queries[i] * QSC);
  } else {
    int j = i - Qq * Dd;
    if (j < Ee * Dd) wb[j] = (unsigned short)f2bf1(W[j]);
  }
}

// ---------------- K2: transpose xn -> xnT bf16 [B][D][N] ------------------
#define TSTRIDE 132
__global__ __launch_bounds__(256) void k_transpose(
    const unsigned short* __restrict__ xn, unsigned short* __restrict__ xnT) {
  __shared__ unsigned short lds[64 * TSTRIDE];
  int bid = blockIdx.x;
  int b = bid >> 8, nt = bid & 255;
  int n0 = nt * 64;
  int t = threadIdx.x;
#pragma unroll
  for (int p = 0; p < 4; ++p) {
    int u = p * 256 + t;          // 1024 units: 64 rows x 16 chunks(8 bf16)
    int r = u >> 4, c = u & 15;
    uint4 d4 = *(const uint4*)(xn + ((size_t)(b * Nn + n0 + r) * Dd + c * 8));
    uint2* dst = (uint2*)&lds[r * TSTRIDE + c * 8];
    dst[0] = make_uint2(d4.x, d4.y);
    dst[1] = make_uint2(d4.z, d4.w);
  }
  __syncthreads();
#pragma unroll
  for (int p = 0; p < 4; ++p) {
    int u = p * 256 + t;          // 1024 units: 128 d-rows x 8 n-groups
    int dr = u >> 3, nc = u & 7;
    unsigned short e0 = lds[(nc * 8 + 0) * TSTRIDE + dr];
    unsigned short e1 = lds[(nc * 8 + 1) * TSTRIDE + dr];
    unsigned short e2 = lds[(nc * 8 + 2) * TSTRIDE + dr];
    unsigned short e3 = lds[(nc * 8 + 3) * TSTRIDE + dr];
    unsigned short e4 = lds[(nc * 8 + 4) * TSTRIDE + dr];
    unsigned short e5 = lds[(nc * 8 + 5) * TSTRIDE + dr];
    unsigned short e6 = lds[(nc * 8 + 6) * TSTRIDE + dr];
    unsigned short e7 = lds[(nc * 8 + 7) * TSTRIDE + dr];
    uint4 o;
    o.x = (unsigned)e0 | ((unsigned)e1 << 16);
    o.y = (unsigned)e2 | ((unsigned)e3 << 16);
    o.z = (unsigned)e4 | ((unsigned)e5 << 16);
    o.w = (unsigned)e6 | ((unsigned)e7 << 16);
    *(uint4*)(xnT + ((size_t)(b * Dd + dr) * Nn + n0 + nc * 8)) = o;
  }
}

// ---------------- K3: cross-attention (no-max softmax, N-split) -----------
// grid 256 = [b 2][qtile 16][split 8], split in low bits for XCD affinity.
// block 512 = 8 waves; each wave owns 32 queries.
__global__ __launch_bounds__(512, 2) void k_attn(
    const unsigned short* __restrict__ xn,   // [B][N][D]
    const unsigned short* __restrict__ xnT,  // [B][D][N]
    const unsigned short* __restrict__ qb,   // [Q][D] prescaled bf16
    float* __restrict__ o_part,              // [B][8][Q][D]
    float* __restrict__ l_part) {            // [B][8][Q]
  __shared__ uint4 lds_x[1024];    // X tile [64 kv][16 chunks] xor-swizzled
  __shared__ uint4 lds_xt[1024];   // Xt tile [128 d][8 chunks] xor-swizzled
  __shared__ uint4 lds_p[2048];    // P per wave [32 q][8 chunks] xor-swizzled

  const int bid = blockIdx.x;
  const int split = bid & 7, qt = (bid >> 3) & 15, b = bid >> 7;
  const int tid = threadIdx.x;
  const int wave = tid >> 6, lane = tid & 63;
  const int col = lane & 15, quad = lane >> 4;
  const int cs = col & 7;
  const int qwbase = qt * 256 + wave * 32;

  // Q fragments in registers (B-operand layout: n=col, k=quad*8+j)
  bf16x8 qf[2][4];
#pragma unroll
  for (int nt = 0; nt < 2; ++nt)
#pragma unroll
    for (int s = 0; s < 4; ++s)
      qf[nt][s] = *(const bf16x8*)(qb + (size_t)(qwbase + nt * 16 + col) * Dd + s * 32 + quad * 8);

  const floatx4 fz = {0.f, 0.f, 0.f, 0.f};
  floatx4 O[2][8];
#pragma unroll
  for (int a = 0; a < 2; ++a)
#pragma unroll
    for (int d = 0; d < 8; ++d) O[a][d] = fz;
  float lsum0 = 0.f, lsum1 = 0.f;

  const uint4* gx = (const uint4*)(xn + (size_t)b * Nn * Dd);
  const uint4* gxt = (const uint4*)(xnT + (size_t)b * Dd * Nn);

  for (int i = 0; i < NITER; ++i) {
    const int nb = split * NCHUNK + i * KV;
    // stage X tile: rows nb..nb+63, 16 chunks of 8 bf16 each
#pragma unroll
    for (int p = 0; p < 2; ++p) {
      int u = p * 512 + tid;
      int r = u >> 4, c = u & 15;
      lds_x[r * 16 + (c ^ (r & 7))] = gx[(size_t)(nb + r) * 16 + c];
    }
    // stage Xt tile: 128 d-rows, 8 chunks each
#pragma unroll
    for (int p = 0; p < 2; ++p) {
      int u = p * 512 + tid;
      int d = u >> 3, c = u & 7;
      lds_xt[d * 8 + (c ^ (d & 7))] = gxt[(size_t)d * (Nn / 8) + (nb / 8) + c];
    }
    __syncthreads();

    // S^T[kv 64][q 32] = X . Q^T  (A = X rows, B = Q rows)
    floatx4 S[4][2];
#pragma unroll
    for (int mt = 0; mt < 4; ++mt) {
      S[mt][0] = fz;
      S[mt][1] = fz;
    }
#pragma unroll
    for (int s = 0; s < 4; ++s) {
#pragma unroll
      for (int mt = 0; mt < 4; ++mt) {
        bf16x8 ax = *(const bf16x8*)&lds_x[(16 * mt + col) * 16 + ((4 * s + quad) ^ cs)];
        S[mt][0] = __builtin_amdgcn_mfma_f32_16x16x32_bf16(ax, qf[0][s], S[mt][0], 0, 0, 0);
        S[mt][1] = __builtin_amdgcn_mfma_f32_16x16x32_bf16(ax, qf[1][s], S[mt][1], 0, 0, 0);
      }
    }

    // p = exp2(s)  (scale*log2e folded into Q); accumulate l; write P to LDS
#pragma unroll
    for (int nt = 0; nt < 2; ++nt) {
#pragma unroll
      for (int mt = 0; mt < 4; ++mt) {
        float p0 = exp2f(S[mt][nt][0]);
        float p1 = exp2f(S[mt][nt][1]);
        float p2 = exp2f(S[mt][nt][2]);
        float p3 = exp2f(S[mt][nt][3]);
        float ps = (p0 + p1) + (p2 + p3);
        if (nt == 0) lsum0 += ps; else lsum1 += ps;
        uint2 pk = make_uint2(f2bf2(p0, p1), f2bf2(p2, p3));
        *(uint2*)((char*)lds_p + wave * 4096 + (nt * 16 + col) * 128 +
                  (((2 * mt + (quad >> 1)) ^ cs) * 16) + 8 * (quad & 1)) = pk;
      }
    }

    // O[q 32][d 128] += P . X   (A = P rows from LDS, B = Xt tile)
#pragma unroll
    for (int s2 = 0; s2 < 2; ++s2) {
      bf16x8 ap0 = *(const bf16x8*)((char*)lds_p + wave * 4096 + col * 128 +
                                    (((4 * s2 + quad) ^ cs) * 16));
      bf16x8 ap1 = *(const bf16x8*)((char*)lds_p + wave * 4096 + (16 + col) * 128 +
                                    (((4 * s2 + quad) ^ cs) * 16));
#pragma unroll
      for (int dn = 0; dn < 8; ++dn) {
        bf16x8 bx = *(const bf16x8*)&lds_xt[(16 * dn + col) * 8 + ((4 * s2 + quad) ^ cs)];
        O[0][dn] = __builtin_amdgcn_mfma_f32_16x16x32_bf16(ap0, bx, O[0][dn], 0, 0, 0);
        O[1][dn] = __builtin_amdgcn_mfma_f32_16x16x32_bf16(ap1, bx, O[1][dn], 0, 0, 0);
      }
    }
    __syncthreads();
  }

  // epilogue: reduce l across quads; store partials
  float lt0 = lsum0 + __shfl_xor(lsum0, 16);
  lt0 += __shfl_xor(lt0, 32);
  float lt1 = lsum1 + __shfl_xor(lsum1, 16);
  lt1 += __shfl_xor(lt1, 32);
  if (quad == 0) {
    size_t lb = (size_t)(b * NSPLIT + split) * Qq + qwbase;
    l_part[lb + col] = lt0;
    l_part[lb + 16 + col] = lt1;
  }
#pragma unroll
  for (int mt2 = 0; mt2 < 2; ++mt2)
#pragma unroll
    for (int dn = 0; dn < 8; ++dn)
#pragma unroll
      for (int r = 0; r < 4; ++r) {
        int q = qwbase + mt2 * 16 + quad * 4 + r;
        o_part[((size_t)(b * NSPLIT + split) * Qq + q) * Dd + dn * 16 + col] = O[mt2][dn][r];
      }
}

// ---------------- K4: combine splits, normalize, trailing GEMM ------------
// grid 64 = [b 2][qchunk 32 of 128 q]; block 256 = 4 waves
__global__ __launch_bounds__(256) void k_comb(
    const float* __restrict__ o_part, const float* __restrict__ l_part,
    const unsigned short* __restrict__ wb, float* __restrict__ out) {
  __shared__ unsigned short lds_a[128 * 136];
  __shared__ float lds_linv[128];
  const int bid = blockIdx.x;
  const int b = bid >> 5, qc = bid & 31;
  const int qbase = qc * 128;
  const int tid = threadIdx.x;
  const int wave = tid >> 6, lane = tid & 63;
  const int col = lane & 15, quad = lane >> 4;

  if (tid < 128) {
    float l = 0.f;
#pragma unroll
    for (int s = 0; s < 8; ++s)
      l += l_part[(size_t)(b * 8 + s) * Qq + qbase + tid];
    lds_linv[tid] = 1.0f / l;
  }
  __syncthreads();

#pragma unroll
  for (int i = 0; i < 16; ++i) {
    int idx = i * 256 + tid;      // 4096 float4 units: q = idx>>5, d4 = idx&31
    int q = idx >> 5, d4 = idx & 31;
    float4 acc = make_float4(0.f, 0.f, 0.f, 0.f);
#pragma unroll
    for (int s = 0; s < 8; ++s) {
      float4 v = *(const float4*)(o_part + ((size_t)(b * 8 + s) * Qq + qbase + q) * Dd + d4 * 4);
      acc.x += v.x; acc.y += v.y; acc.z += v.z; acc.w += v.w;
    }
    float li = lds_linv[q];
    uint2 pk = make_uint2(f2bf2(acc.x * li, acc.y * li), f2bf2(acc.z * li, acc.w * li));
    *(uint2*)((char*)lds_a + ((size_t)q * 136 + d4 * 4) * 2) = pk;
  }
  __syncthreads();

  bf16x8 af[2][4];
#pragma unroll
  for (int mt = 0; mt < 2; ++mt)
#pragma unroll
    for (int s = 0; s < 4; ++s)
      af[mt][s] = *(const bf16x8*)&lds_a[(wave * 32 + mt * 16 + col) * 136 + s * 32 + quad * 8];

  const floatx4 fz = {0.f, 0.f, 0.f, 0.f};
#pragma unroll
  for (int en = 0; en < 16; ++en) {
    floatx4 C0 = fz, C1 = fz;
#pragma unroll
    for (int s = 0; s < 4; ++s) {
      bf16x8 bw = *(const bf16x8*)(wb + (size_t)(en * 16 + col) * Dd + s * 32 + quad * 8);
      C0 = __builtin_amdgcn_mfma_f32_16x16x32_bf16(af[0][s], bw, C0, 0, 0, 0);
      C1 = __builtin_amdgcn_mfma_f32_16x16x32_bf16(af[1][s], bw, C1, 0, 0, 0);
    }
#pragma unroll
    for (int r = 0; r < 4; ++r) {
      int q0 = qbase + wave * 32 + quad * 4 + r;
      out[((size_t)b * Qq + q0) * Ee + en * 16 + col] = C0[r];
      out[((size_t)b * Qq + q0 + 16) * Ee + en * 16 + col] = C1[r];
    }
  }
}

// ---------------- launcher ------------------------------------------------
extern "C" void kernel_launch(void* const* d_in, const int* in_sizes, int n_in,
                              void* d_out, int out_size, void* d_ws, size_t ws_size,
                              hipStream_t stream) {
  const float* x = (const float*)d_in[0];
  const float* gamma = (const float*)d_in[1];
  const float* beta = (const float*)d_in[2];
  const float* queries = (const float*)d_in[3];
  const float* W = (const float*)d_in[4];
  float* out = (float*)d_out;

  char* w = (char*)d_ws;
  unsigned short* xn = (unsigned short*)(w);                  // 8 MB
  unsigned short* xnT = (unsigned short*)(w + 8388608);       // 8 MB
  unsigned short* qb = (unsigned short*)(w + 16777216);       // 1 MB
  unsigned short* wb = (unsigned short*)(w + 17825792);       // 64 KB
  float* o_part = (float*)(w + 17891328);                     // 32 MB
  float* l_part = (float*)(w + 51445760);                     // 256 KB

  k_ln<<<dim3(8192), dim3(256), 0, stream>>>(x, gamma, beta, (unsigned*)xn);
  k_cast<<<dim3(2176), dim3(256), 0, stream>>>(queries, W, qb, wb);
  k_transpose<<<dim3(512), dim3(256), 0, stream>>>(xn, xnT);
  k_attn<<<dim3(256), dim3(512), 0, stream>>>(xn, xnT, qb, o_part, l_part);
  k_comb<<<dim3(64), dim3(256), 0, stream>>>(o_part, l_part, wb, out);
}

// Round 2
// 185.593 us; speedup vs baseline: 1.0489x; 1.0489x over previous
//
#include <hip/hip_runtime.h>
#include <stdint.h>

#define Nn 16384
#define Dd 128
#define Qq 4096
#define Ee 256
#define NSPLIT 8
#define NCHUNK 2048   // Nn / NSPLIT
#define KV 64
#define NITER 32      // NCHUNK / KV

typedef __bf16 bf16x8 __attribute__((ext_vector_type(8)));
typedef float floatx4 __attribute__((ext_vector_type(4)));

__device__ __forceinline__ float fexp2(float x) {
#if __has_builtin(__builtin_amdgcn_exp2f)
  return __builtin_amdgcn_exp2f(x);
#else
  return exp2f(x);
#endif
}
// pack two f32 -> bf16x2 (round-half-up, 3 VALU ops)
__device__ __forceinline__ unsigned pk_bf(float lo, float hi) {
  return __builtin_amdgcn_perm(__float_as_uint(hi) + 0x8000u,
                               __float_as_uint(lo) + 0x8000u, 0x07060302u);
}
__device__ __forceinline__ unsigned short bf1(float f) {
  return (unsigned short)((__float_as_uint(f) + 0x8000u) >> 16);
}

// ---- K1: fused LayerNorm + bf16 cast + transpose + q/W cast --------------
// grid 512 = [b 2][ntile 256 of 64 rows]; block 256.
// thread: row r = tid>>2 (64 rows), quarter qd = tid&3 (32 d each).
__global__ __launch_bounds__(256) void k_lnt(
    const float* __restrict__ x, const float* __restrict__ gamma,
    const float* __restrict__ beta, const float* __restrict__ queries,
    const float* __restrict__ W, unsigned* __restrict__ xn,
    unsigned short* __restrict__ xnT, unsigned short* __restrict__ qb,
    unsigned short* __restrict__ wb) {
  __shared__ uint2 lds2[64 * 32];   // [row][d-quad unit], xor-swizzled
  const int tid = threadIdx.x;
  const int bid = blockIdx.x;
  const int b = bid >> 8, n0 = (bid & 255) * 64;
  const int r = tid >> 2, qd = tid & 3;

  const float4* xp = (const float4*)(x + ((size_t)(b * Nn + n0 + r)) * Dd + qd * 32);
  float4 v[8];
  float s = 0.f, s2 = 0.f;
#pragma unroll
  for (int i = 0; i < 8; ++i) {
    v[i] = xp[i];
    s += (v[i].x + v[i].y) + (v[i].z + v[i].w);
    s2 += (v[i].x * v[i].x + v[i].y * v[i].y) + (v[i].z * v[i].z + v[i].w * v[i].w);
  }
  s += __shfl_xor(s, 1); s2 += __shfl_xor(s2, 1);
  s += __shfl_xor(s, 2); s2 += __shfl_xor(s2, 2);
  float mu = s * (1.0f / 128.0f);
  float var = s2 * (1.0f / 128.0f) - mu * mu;
  float rs = rsqrtf(var + 1e-5f);

  const float4* gp = (const float4*)(gamma + qd * 32);
  const float4* bp = (const float4*)(beta + qd * 32);
  unsigned pk[16];
#pragma unroll
  for (int i = 0; i < 8; ++i) {
    float4 g = gp[i], bt = bp[i];
    float y0 = (v[i].x - mu) * rs * g.x + bt.x;
    float y1 = (v[i].y - mu) * rs * g.y + bt.y;
    float y2 = (v[i].z - mu) * rs * g.z + bt.z;
    float y3 = (v[i].w - mu) * rs * g.w + bt.w;
    pk[2 * i] = pk_bf(y0, y1);
    pk[2 * i + 1] = pk_bf(y2, y3);
  }
  // xn write (row-major, contiguous)
  uint4* xo = (uint4*)(xn + ((size_t)(b * Nn + n0 + r)) * 64 + qd * 16);
#pragma unroll
  for (int i = 0; i < 4; ++i)
    xo[i] = make_uint4(pk[4 * i], pk[4 * i + 1], pk[4 * i + 2], pk[4 * i + 3]);
  // LDS for transpose: uint2 unit m holds d = 4m..4m+3 of row r
  const int rk = r & 31;
#pragma unroll
  for (int kk = 0; kk < 8; ++kk)
    lds2[r * 32 + ((qd * 8 + kk) ^ rk)] = make_uint2(pk[2 * kk], pk[2 * kk + 1]);
  __syncthreads();
  // transpose: thread -> d-quad dq, n-group nc
  const int dq = tid >> 3, nc = tid & 7;
  uint2 U[8];
#pragma unroll
  for (int j = 0; j < 8; ++j) {
    int rr = nc * 8 + j;
    U[j] = lds2[rr * 32 + (dq ^ (rr & 31))];
  }
#pragma unroll
  for (int e = 0; e < 4; ++e) {
    unsigned a0 = (e & 2) ? U[0].y : U[0].x, a1 = (e & 2) ? U[1].y : U[1].x;
    unsigned a2 = (e & 2) ? U[2].y : U[2].x, a3 = (e & 2) ? U[3].y : U[3].x;
    unsigned a4 = (e & 2) ? U[4].y : U[4].x, a5 = (e & 2) ? U[5].y : U[5].x;
    unsigned a6 = (e & 2) ? U[6].y : U[6].x, a7 = (e & 2) ? U[7].y : U[7].x;
    unsigned sel = (e & 1) ? 0x07060302u : 0x05040100u;
    uint4 o;
    o.x = __builtin_amdgcn_perm(a1, a0, sel);
    o.y = __builtin_amdgcn_perm(a3, a2, sel);
    o.z = __builtin_amdgcn_perm(a5, a4, sel);
    o.w = __builtin_amdgcn_perm(a7, a6, sel);
    *(uint4*)(xnT + ((size_t)(b * Dd + dq * 4 + e)) * Nn + n0 + nc * 8) = o;
  }
  // fold-in: cast queries (prescaled) and W to bf16
  const float QSC = 0.08838834764831845f * 1.4426950408889634f; // D^-0.5 * log2e
  for (int idx = bid * 256 + tid; idx < Qq * Dd + Ee * Dd; idx += 512 * 256) {
    if (idx < Qq * Dd) qb[idx] = bf1(queries[idx] * QSC);
    else wb[idx - Qq * Dd] = bf1(W[idx - Qq * Dd]);
  }
}

// ---- K2: cross-attention (no-max softmax, N-split) -----------------------
// grid 512 = [b 2][qtile 32 of 128 q][split 8] (split in low bits: XCD affinity)
// block 512 = 8 waves; each wave owns 16 queries. 2 blocks/CU.
__global__ __launch_bounds__(512, 4) void k_attn(
    const unsigned short* __restrict__ xn,   // [B][N][D]
    const unsigned short* __restrict__ xnT,  // [B][D][N]
    const unsigned short* __restrict__ qb,   // [Q][D] prescaled bf16
    float* __restrict__ o_part,              // [B][8][Q][D]
    float* __restrict__ l_part) {            // [B][8][Q]
  __shared__ uint4 lds_x[1024];    // X tile [64 kv][16 chunks] xor-swizzled
  __shared__ uint4 lds_xt[1024];   // Xt tile [128 d][8 chunks] xor-swizzled
  __shared__ char lds_p[16384];    // P per wave [16 q][64 kv] xor-swizzled

  const int bid = blockIdx.x;
  const int split = bid & 7, qt = (bid >> 3) & 31, b = bid >> 8;
  const int tid = threadIdx.x;
  const int wave = tid >> 6, lane = tid & 63;
  const int col = lane & 15, quad = lane >> 4;
  const int cs = col & 7;
  const int qwbase = qt * 128 + wave * 16;

  // Q fragments (B-operand layout: n=col, k=quad*8+j)
  bf16x8 qf[4];
#pragma unroll
  for (int s = 0; s < 4; ++s)
    qf[s] = *(const bf16x8*)(qb + (size_t)(qwbase + col) * Dd + s * 32 + quad * 8);

  const floatx4 fz = {0.f, 0.f, 0.f, 0.f};
  floatx4 O[8];
#pragma unroll
  for (int d = 0; d < 8; ++d) O[d] = fz;
  float lsum = 0.f;

  const uint4* gx = (const uint4*)(xn + (size_t)b * Nn * Dd);
  const uint4* gxt = (const uint4*)(xnT + (size_t)b * Dd * Nn);

  for (int i = 0; i < NITER; ++i) {
    const int nb = split * NCHUNK + i * KV;
#pragma unroll
    for (int p = 0; p < 2; ++p) {   // X tile: 64 rows x 16 chunks
      int u = p * 512 + tid;
      int rr = u >> 4, c = u & 15;
      lds_x[rr * 16 + (c ^ (rr & 7))] = gx[(size_t)(nb + rr) * 16 + c];
    }
#pragma unroll
    for (int p = 0; p < 2; ++p) {   // Xt tile: 128 d-rows x 8 chunks
      int u = p * 512 + tid;
      int d = u >> 3, c = u & 7;
      lds_xt[d * 8 + (c ^ (d & 7))] = gxt[(size_t)d * (Nn / 8) + (nb / 8) + c];
    }
    __syncthreads();

    // S^T[kv 64][q 16] = X . Q^T
    floatx4 S[4];
#pragma unroll
    for (int mt = 0; mt < 4; ++mt) S[mt] = fz;
#pragma unroll
    for (int s = 0; s < 4; ++s)
#pragma unroll
      for (int mt = 0; mt < 4; ++mt) {
        bf16x8 ax = *(const bf16x8*)&lds_x[(16 * mt + col) * 16 + ((4 * s + quad) ^ cs)];
        S[mt] = __builtin_amdgcn_mfma_f32_16x16x32_bf16(ax, qf[s], S[mt], 0, 0, 0);
      }

    // p = exp2(s); accumulate l; P -> LDS (per-wave region, no barrier)
#pragma unroll
    for (int mt = 0; mt < 4; ++mt) {
      float p0 = fexp2(S[mt][0]);
      float p1 = fexp2(S[mt][1]);
      float p2 = fexp2(S[mt][2]);
      float p3 = fexp2(S[mt][3]);
      lsum += (p0 + p1) + (p2 + p3);
      *(uint2*)(lds_p + wave * 2048 + col * 128 +
                (((2 * mt + (quad >> 1)) ^ cs) * 16) + (quad & 1) * 8) =
          make_uint2(pk_bf(p0, p1), pk_bf(p2, p3));
    }

    // O[q 16][d 128] += P . X
#pragma unroll
    for (int s2 = 0; s2 < 2; ++s2) {
      bf16x8 ap = *(const bf16x8*)(lds_p + wave * 2048 + col * 128 +
                                   (((4 * s2 + quad) ^ cs) * 16));
#pragma unroll
      for (int dn = 0; dn < 8; ++dn) {
        bf16x8 bx = *(const bf16x8*)&lds_xt[(16 * dn + col) * 8 + ((4 * s2 + quad) ^ cs)];
        O[dn] = __builtin_amdgcn_mfma_f32_16x16x32_bf16(ap, bx, O[dn], 0, 0, 0);
      }
    }
    __syncthreads();
  }

  float lt = lsum + __shfl_xor(lsum, 16);
  lt += __shfl_xor(lt, 32);
  if (quad == 0)
    l_part[(size_t)(b * NSPLIT + split) * Qq + qwbase + col] = lt;
#pragma unroll
  for (int dn = 0; dn < 8; ++dn)
#pragma unroll
    for (int r = 0; r < 4; ++r) {
      int q = qwbase + quad * 4 + r;
      o_part[((size_t)(b * NSPLIT + split) * Qq + q) * Dd + dn * 16 + col] = O[dn][r];
    }
}

// ---- K3: combine splits, normalize, trailing GEMM ------------------------
// grid 128 = [b 2][qchunk 64 of 64 q]; block 256 = 4 waves (16 q each)
__global__ __launch_bounds__(256) void k_comb(
    const float* __restrict__ o_part, const float* __restrict__ l_part,
    const unsigned short* __restrict__ wb, float* __restrict__ out) {
  __shared__ unsigned short lds_a[64 * 136];
  __shared__ float lds_linv[64];
  const int bid = blockIdx.x;
  const int b = bid >> 6, qc = bid & 63;
  const int qbase = qc * 64;
  const int tid = threadIdx.x;
  const int wave = tid >> 6, lane = tid & 63;
  const int col = lane & 15, quad = lane >> 4;

  if (tid < 64) {
    float l = 0.f;
#pragma unroll
    for (int s = 0; s < 8; ++s)
      l += l_part[(size_t)(b * 8 + s) * Qq + qbase + tid];
    lds_linv[tid] = 1.0f / l;
  }
  __syncthreads();

#pragma unroll
  for (int i = 0; i < 8; ++i) {
    int idx = i * 256 + tid;      // 2048 float4 units: q = idx>>5, d4 = idx&31
    int q = idx >> 5, d4 = idx & 31;
    float4 acc = make_float4(0.f, 0.f, 0.f, 0.f);
#pragma unroll
    for (int s = 0; s < 8; ++s) {
      float4 v = *(const float4*)(o_part + ((size_t)(b * 8 + s) * Qq + qbase + q) * Dd + d4 * 4);
      acc.x += v.x; acc.y += v.y; acc.z += v.z; acc.w += v.w;
    }
    float li = lds_linv[q];
    *(uint2*)((char*)lds_a + (size_t)q * 272 + d4 * 8) =
        make_uint2(pk_bf(acc.x * li, acc.y * li), pk_bf(acc.z * li, acc.w * li));
  }
  __syncthreads();

  bf16x8 af[4];
#pragma unroll
  for (int s = 0; s < 4; ++s)
    af[s] = *(const bf16x8*)&lds_a[(wave * 16 + col) * 136 + s * 32 + quad * 8];

  const floatx4 fz = {0.f, 0.f, 0.f, 0.f};
#pragma unroll
  for (int en = 0; en < 16; ++en) {
    floatx4 C = fz;
#pragma unroll
    for (int s = 0; s < 4; ++s) {
      bf16x8 bw = *(const bf16x8*)(wb + (size_t)(en * 16 + col) * Dd + s * 32 + quad * 8);
      C = __builtin_amdgcn_mfma_f32_16x16x32_bf16(af[s], bw, C, 0, 0, 0);
    }
#pragma unroll
    for (int r = 0; r < 4; ++r) {
      int q0 = qbase + wave * 16 + quad * 4 + r;
      out[((size_t)b * Qq + q0) * Ee + en * 16 + col] = C[r];
    }
  }
}

// ---- launcher ------------------------------------------------------------
extern "C" void kernel_launch(void* const* d_in, const int* in_sizes, int n_in,
                              void* d_out, int out_size, void* d_ws, size_t ws_size,
                              hipStream_t stream) {
  const float* x = (const float*)d_in[0];
  const float* gamma = (const float*)d_in[1];
  const float* beta = (const float*)d_in[2];
  const float* queries = (const float*)d_in[3];
  const float* W = (const float*)d_in[4];
  float* out = (float*)d_out;

  char* w = (char*)d_ws;
  unsigned short* xn = (unsigned short*)(w);                  // 8 MB
  unsigned short* xnT = (unsigned short*)(w + 8388608);       // 8 MB
  unsigned short* qb = (unsigned short*)(w + 16777216);       // 1 MB
  unsigned short* wb = (unsigned short*)(w + 17825792);       // 64 KB
  float* o_part = (float*)(w + 17891328);                     // 32 MB
  float* l_part = (float*)(w + 51445760);                     // 256 KB

  k_lnt<<<dim3(512), dim3(256), 0, stream>>>(x, gamma, beta, queries, W,
                                             (unsigned*)xn, xnT, qb, wb);
  k_attn<<<dim3(512), dim3(512), 0, stream>>>(xn, xnT, qb, o_part, l_part);
  k_comb<<<dim3(128), dim3(256), 0, stream>>>(o_part, l_part, wb, out);
}

// Round 4
// 168.080 us; speedup vs baseline: 1.1581x; 1.1042x over previous
//
#include <hip/hip_runtime.h>
#include <stdint.h>

#define Nn 16384
#define Dd 128
#define Qq 4096
#define Ee 256
#define NSPLIT 8
#define NCHUNK 2048   // Nn / NSPLIT
#define KV 64
#define NITER 32      // NCHUNK / KV

typedef __bf16 bf16x8 __attribute__((ext_vector_type(8)));
typedef float floatx16 __attribute__((ext_vector_type(16)));

__device__ __forceinline__ float fexp2(float x) {
#if __has_builtin(__builtin_amdgcn_exp2f)
  return __builtin_amdgcn_exp2f(x);
#else
  return exp2f(x);
#endif
}
// pack two f32 -> bf16x2 (round-half-up, 3 VALU ops)
__device__ __forceinline__ unsigned pk_bf(float lo, float hi) {
  return __builtin_amdgcn_perm(__float_as_uint(hi) + 0x8000u,
                               __float_as_uint(lo) + 0x8000u, 0x07060302u);
}
// async global->LDS, 16B per lane; lds dest = wave-uniform base + lane*16
__device__ __forceinline__ void stage16(const void* g, void* lds_uniform) {
  __builtin_amdgcn_global_load_lds(
      (const __attribute__((address_space(1))) unsigned int*)g,
      (__attribute__((address_space(3))) unsigned int*)lds_uniform, 16, 0, 0);
}

// ---- K1: fused LayerNorm + bf16 cast (swizzled) + transpose + q/W cast ---
// grid 512 = [b 2][ntile 256 of 64 rows]; block 256.
// xn global layout: row n (256B), 16B-unit c stored at c ^ (n&7).
// xnT global layout: row d (32KB), within each 64-n window unit g at g^(d&7).
__global__ __launch_bounds__(256) void k_lnt(
    const float* __restrict__ x, const float* __restrict__ gamma,
    const float* __restrict__ beta, const float* __restrict__ queries,
    const float* __restrict__ W, unsigned* __restrict__ xn,
    unsigned short* __restrict__ xnT, unsigned short* __restrict__ qb,
    unsigned short* __restrict__ wb) {
  __shared__ __align__(16) uint2 lds2[64 * 32];   // [row][d-quad], xor-swizzled
  const int tid = threadIdx.x;
  const int bid = blockIdx.x;
  const int b = bid >> 8, n0 = (bid & 255) * 64;
  const int r = tid >> 2, qd = tid & 3;

  const float4* xp = (const float4*)(x + ((size_t)(b * Nn + n0 + r)) * Dd + qd * 32);
  float4 v[8];
  float s = 0.f, s2 = 0.f;
#pragma unroll
  for (int i = 0; i < 8; ++i) {
    v[i] = xp[i];
    s += (v[i].x + v[i].y) + (v[i].z + v[i].w);
    s2 += (v[i].x * v[i].x + v[i].y * v[i].y) + (v[i].z * v[i].z + v[i].w * v[i].w);
  }
  s += __shfl_xor(s, 1); s2 += __shfl_xor(s2, 1);
  s += __shfl_xor(s, 2); s2 += __shfl_xor(s2, 2);
  float mu = s * (1.0f / 128.0f);
  float var = s2 * (1.0f / 128.0f) - mu * mu;
  float rs = rsqrtf(var + 1e-5f);

  const float4* gp = (const float4*)(gamma + qd * 32);
  const float4* bp = (const float4*)(beta + qd * 32);
  unsigned pk[16];
#pragma unroll
  for (int i = 0; i < 8; ++i) {
    float4 g = gp[i], bt = bp[i];
    pk[2 * i] = pk_bf((v[i].x - mu) * rs * g.x + bt.x, (v[i].y - mu) * rs * g.y + bt.y);
    pk[2 * i + 1] = pk_bf((v[i].z - mu) * rs * g.z + bt.z, (v[i].w - mu) * rs * g.w + bt.w);
  }
  // xn write: 16B unit c = qd*4+j stored at position c ^ (r&7)
  unsigned* xrow = xn + ((size_t)(b * Nn + n0 + r)) * 64;
#pragma unroll
  for (int j = 0; j < 4; ++j)
    *(uint4*)(xrow + (((qd * 4 + j) ^ (r & 7)) * 4)) =
        make_uint4(pk[4 * j], pk[4 * j + 1], pk[4 * j + 2], pk[4 * j + 3]);
  // LDS for transpose: uint2 unit m holds d = 4m..4m+3 of row r
  const int rk = r & 31;
#pragma unroll
  for (int kk = 0; kk < 8; ++kk)
    lds2[r * 32 + ((qd * 8 + kk) ^ rk)] = make_uint2(pk[2 * kk], pk[2 * kk + 1]);
  __syncthreads();
  // transpose: thread -> d-quad dq, n-group nc
  const int dq = tid >> 3, nc = tid & 7;
  uint2 U[8];
#pragma unroll
  for (int j = 0; j < 8; ++j) {
    int rr = nc * 8 + j;
    U[j] = lds2[rr * 32 + (dq ^ (rr & 31))];
  }
#pragma unroll
  for (int e = 0; e < 4; ++e) {
    int d = dq * 4 + e;
    unsigned a0 = (e & 2) ? U[0].y : U[0].x, a1 = (e & 2) ? U[1].y : U[1].x;
    unsigned a2 = (e & 2) ? U[2].y : U[2].x, a3 = (e & 2) ? U[3].y : U[3].x;
    unsigned a4 = (e & 2) ? U[4].y : U[4].x, a5 = (e & 2) ? U[5].y : U[5].x;
    unsigned a6 = (e & 2) ? U[6].y : U[6].x, a7 = (e & 2) ? U[7].y : U[7].x;
    unsigned sel = (e & 1) ? 0x07060302u : 0x05040100u;
    uint4 o;
    o.x = __builtin_amdgcn_perm(a1, a0, sel);
    o.y = __builtin_amdgcn_perm(a3, a2, sel);
    o.z = __builtin_amdgcn_perm(a5, a4, sel);
    o.w = __builtin_amdgcn_perm(a7, a6, sel);
    *(uint4*)(xnT + ((size_t)(b * Dd + d)) * Nn + n0 + (nc ^ (d & 7)) * 8) = o;
  }
  // fold-in: cast queries (prescaled) and W to bf16, vectorized
  const float QSC = 0.08838834764831845f * 1.4426950408889634f; // D^-0.5 * log2e
  const int total4 = (Qq * Dd + Ee * Dd) / 4;
  for (int u = bid * 256 + tid; u < total4; u += 512 * 256) {
    if (u < Qq * Dd / 4) {
      float4 v4 = ((const float4*)queries)[u];
      ((uint2*)qb)[u] = make_uint2(pk_bf(v4.x * QSC, v4.y * QSC),
                                   pk_bf(v4.z * QSC, v4.w * QSC));
    } else {
      float4 v4 = ((const float4*)W)[u - Qq * Dd / 4];
      ((uint2*)wb)[u - Qq * Dd / 4] =
          make_uint2(pk_bf(v4.x, v4.y), pk_bf(v4.z, v4.w));
    }
  }
}

// ---- K2: cross-attention, 32x32x16 MFMA, async staging -------------------
// grid 512 = [b 2][qtile 32 of 128 q][split 8]; block 256 = 4 waves x 32 q.
__global__ __launch_bounds__(256, 2) void k_attn(
    const unsigned short* __restrict__ xn,   // [B][N][D] swizzled
    const unsigned short* __restrict__ xnT,  // [B][D][N] swizzled
    const unsigned short* __restrict__ qb,   // [Q][D] prescaled bf16
    float* __restrict__ o_part,              // [B][8][Q][D]
    float* __restrict__ l_part) {            // [B][8][Q]
  __shared__ __align__(16) char lds[49152];
  char* lds_x = lds;            // 16 KB: [64 kv][16 units], unit u at u^(kv&7)
  char* lds_xt = lds + 16384;   // 16 KB: [128 d][8 units], unit u at u^(d&7)
  char* lds_p = lds + 32768;    // 16 KB: wave*[32 q][8 units], unit u at u^(q&7)

  const int bid = blockIdx.x;
  const int split = bid & 7, qt = (bid >> 3) & 31, b = bid >> 8;
  const int tid = threadIdx.x;
  const int wave = tid >> 6, lane = tid & 63;
  const int col = lane & 31, half = lane >> 5;
  const int ck = col & 7;
  const int qwbase = qt * 128 + wave * 32;

  // Q B-fragments in registers: n=col, k=half*8+j per 16-k step
  bf16x8 qf[8];
#pragma unroll
  for (int s = 0; s < 8; ++s)
    qf[s] = *(const bf16x8*)(qb + (size_t)(qwbase + col) * Dd + s * 16 + half * 8);

  const floatx16 fz = {0.f,0.f,0.f,0.f,0.f,0.f,0.f,0.f,0.f,0.f,0.f,0.f,0.f,0.f,0.f,0.f};
  floatx16 O[4];
#pragma unroll
  for (int d = 0; d < 4; ++d) O[d] = fz;
  float lsum = 0.f;

  const char* gx = (const char*)xn + (size_t)b * Nn * 256;
  const char* gxt = (const char*)xnT + (size_t)b * Dd * Nn * 2;
  char* ldsp_w = lds_p + wave * 4096;

  for (int i = 0; i < NITER; ++i) {
    const int nb = split * NCHUNK + i * KV;
    // stage X tile (16 KB contiguous) + Xt tile (128 rows x 128 B)
    const char* xsrc = gx + (size_t)nb * 256;
#pragma unroll
    for (int p = 0; p < 4; ++p) {
      int m = wave * 4 + p;
      stage16(xsrc + m * 1024 + lane * 16, lds_x + m * 1024);
    }
#pragma unroll
    for (int p = 0; p < 4; ++p) {
      int m = wave * 4 + p;
      const char* g = gxt + (size_t)(m * 8 + (lane >> 3)) * (Nn * 2) +
                      (size_t)nb * 2 + (lane & 7) * 16;
      stage16(g, lds_xt + m * 1024);
    }
    __syncthreads();

    // S^T[kv 64][q 32] = X(A) . Q^T(B)
    floatx16 S[2];
    S[0] = fz; S[1] = fz;
#pragma unroll
    for (int s = 0; s < 8; ++s)
#pragma unroll
      for (int mt = 0; mt < 2; ++mt) {
        bf16x8 ax = *(const bf16x8*)(lds_x + (32 * mt + col) * 256 +
                                     (((2 * s + half) ^ ck) * 16));
        S[mt] = __builtin_amdgcn_mfma_f32_32x32x16_bf16(ax, qf[s], S[mt], 0, 0, 0);
      }

    // p = exp2(s); accumulate l; P -> per-wave LDS (no barrier needed)
#pragma unroll
    for (int mt = 0; mt < 2; ++mt)
#pragma unroll
      for (int t = 0; t < 4; ++t) {
        float p0 = fexp2(S[mt][4 * t]);
        float p1 = fexp2(S[mt][4 * t + 1]);
        float p2 = fexp2(S[mt][4 * t + 2]);
        float p3 = fexp2(S[mt][4 * t + 3]);
        lsum += (p0 + p1) + (p2 + p3);
        int w = 4 * mt + t;   // kv unit (16B = 8 kv); within-unit ofs 4*half+rr
        *(uint2*)(ldsp_w + col * 128 + ((w ^ ck) * 16) + half * 8) =
            make_uint2(pk_bf(p0, p1), pk_bf(p2, p3));
      }

    // O[q 32][d 128] += P(A) . Xt(B)
#pragma unroll
    for (int s2 = 0; s2 < 4; ++s2) {
      bf16x8 ap = *(const bf16x8*)(ldsp_w + col * 128 + (((2 * s2 + half) ^ ck) * 16));
#pragma unroll
      for (int dn = 0; dn < 4; ++dn) {
        bf16x8 bx = *(const bf16x8*)(lds_xt + (32 * dn + col) * 128 +
                                     (((2 * s2 + half) ^ ck) * 16));
        O[dn] = __builtin_amdgcn_mfma_f32_32x32x16_bf16(ap, bx, O[dn], 0, 0, 0);
      }
    }
    __syncthreads();
  }

  // epilogue
  float lt = lsum + __shfl_xor(lsum, 32);
  if (half == 0)
    l_part[(size_t)(b * NSPLIT + split) * Qq + qwbase + col] = lt;
  float* op = o_part + ((size_t)(b * NSPLIT + split) * Qq + qwbase) * Dd;
#pragma unroll
  for (int dn = 0; dn < 4; ++dn)
#pragma unroll
    for (int r = 0; r < 16; ++r) {
      int q = (r & 3) + 8 * (r >> 2) + 4 * half;
      op[(size_t)q * Dd + dn * 32 + col] = O[dn][r];
    }
}

// ---- K3: combine splits, normalize, trailing GEMM (32x32x16) -------------
// grid 256 = [b 2][qchunk 128 of 32 q]; block 256 = 4 waves (wave owns 64 E)
// lds_a: [32 q][16 units of 16B] stride 256B; unit u at (u&8)|((u^ (q&7))&7)
__global__ __launch_bounds__(256) void k_comb(
    const float* __restrict__ o_part, const float* __restrict__ l_part,
    const unsigned short* __restrict__ wb, float* __restrict__ out) {
  __shared__ __align__(16) char lds_a[32 * 256];
  __shared__ float lds_linv[32];
  const int bid = blockIdx.x;
  const int b = bid >> 7, qc = bid & 127;
  const int qbase = qc * 32;
  const int tid = threadIdx.x;
  const int wave = tid >> 6, lane = tid & 63;
  const int col = lane & 31, half = lane >> 5;
  const int ck = col & 7;

  if (tid < 32) {
    float l = 0.f;
#pragma unroll
    for (int s = 0; s < 8; ++s)
      l += l_part[(size_t)(b * 8 + s) * Qq + qbase + tid];
    lds_linv[tid] = 1.0f / l;
  }
  __syncthreads();

#pragma unroll
  for (int i = 0; i < 4; ++i) {
    int idx = i * 256 + tid;      // 1024 float4 units: q = idx>>5, d4 = idx&31
    int q = idx >> 5, d4 = idx & 31;
    float4 acc = make_float4(0.f, 0.f, 0.f, 0.f);
#pragma unroll
    for (int s = 0; s < 8; ++s) {
      float4 v = *(const float4*)(o_part + ((size_t)(b * 8 + s) * Qq + qbase + q) * Dd + d4 * 4);
      acc.x += v.x; acc.y += v.y; acc.z += v.z; acc.w += v.w;
    }
    float li = lds_linv[q];
    int w = d4 >> 1;                          // 16B unit = 8 d values
    int pos = (w & 8) | ((w ^ (q & 7)) & 7);  // swizzle low 3 bits only
    *(uint2*)(lds_a + q * 256 + pos * 16 + (d4 & 1) * 8) =
        make_uint2(pk_bf(acc.x * li, acc.y * li), pk_bf(acc.z * li, acc.w * li));
  }
  __syncthreads();

  bf16x8 af[8];
#pragma unroll
  for (int s = 0; s < 8; ++s) {
    int u = 2 * s + half;
    int pos = (u & 8) | ((u ^ ck) & 7);
    af[s] = *(const bf16x8*)(lds_a + col * 256 + pos * 16);
  }

  const floatx16 fz = {0.f,0.f,0.f,0.f,0.f,0.f,0.f,0.f,0.f,0.f,0.f,0.f,0.f,0.f,0.f,0.f};
#pragma unroll
  for (int et = 0; et < 2; ++et) {
    floatx16 C = fz;
    int e_row = wave * 64 + et * 32 + col;
#pragma unroll
    for (int s = 0; s < 8; ++s) {
      bf16x8 bw = *(const bf16x8*)(wb + (size_t)e_row * Dd + s * 16 + half * 8);
      C = __builtin_amdgcn_mfma_f32_32x32x16_bf16(af[s], bw, C, 0, 0, 0);
    }
#pragma unroll
    for (int r = 0; r < 16; ++r) {
      int q = qbase + (r & 3) + 8 * (r >> 2) + 4 * half;
      out[((size_t)b * Qq + q) * Ee + wave * 64 + et * 32 + col] = C[r];
    }
  }
}

// ---- launcher ------------------------------------------------------------
extern "C" void kernel_launch(void* const* d_in, const int* in_sizes, int n_in,
                              void* d_out, int out_size, void* d_ws, size_t ws_size,
                              hipStream_t stream) {
  const float* x = (const float*)d_in[0];
  const float* gamma = (const float*)d_in[1];
  const float* beta = (const float*)d_in[2];
  const float* queries = (const float*)d_in[3];
  const float* W = (const float*)d_in[4];
  float* out = (float*)d_out;

  char* w = (char*)d_ws;
  unsigned short* xn = (unsigned short*)(w);                  // 8 MB
  unsigned short* xnT = (unsigned short*)(w + 8388608);       // 8 MB
  unsigned short* qb = (unsigned short*)(w + 16777216);       // 1 MB
  unsigned short* wb = (unsigned short*)(w + 17825792);       // 64 KB
  float* o_part = (float*)(w + 17891328);                     // 32 MB
  float* l_part = (float*)(w + 51445760);                     // 256 KB

  k_lnt<<<dim3(512), dim3(256), 0, stream>>>(x, gamma, beta, queries, W,
                                             (unsigned*)xn, xnT, qb, wb);
  k_attn<<<dim3(512), dim3(256), 0, stream>>>(xn, xnT, qb, o_part, l_part);
  k_comb<<<dim3(256), dim3(256), 0, stream>>>(o_part, l_part, wb, out);
}